// Round 1
// baseline (3752.441 us; speedup 1.0000x reference)
//
#include <hip/hip_runtime.h>
#include <math.h>

#define BB 8
#define TT 4096
#define DDIM 512
#define KK 4096
#define NN (BB*TT)

#define BM 64
#define BN 64
#define BD 64
#define LSTR (BD + 4)   // 68 floats: 16B-aligned rows, breaks power-of-2 bank strides

// ---------------- kernel 1: per-row sum of squares ----------------
// mode 0: out[r] = sum(src[r]^2)          (for embed -> e_sq)
// mode 1: out[r] = 1/max(sqrt(ss),1e-12)  (for x -> inv_norm)
__global__ __launch_bounds__(256) void rowss_kernel(const float* __restrict__ src,
                                                    float* __restrict__ out, int mode) {
  int r = blockIdx.x * 4 + (threadIdx.x >> 6);   // one wave per row
  int lane = threadIdx.x & 63;
  const float4* row4 = (const float4*)(src + (size_t)r * DDIM);
  float4 v0 = row4[lane];
  float4 v1 = row4[lane + 64];
  float ss = v0.x*v0.x + v0.y*v0.y + v0.z*v0.z + v0.w*v0.w
           + v1.x*v1.x + v1.y*v1.y + v1.z*v1.z + v1.w*v1.w;
  #pragma unroll
  for (int off = 32; off; off >>= 1) ss += __shfl_down(ss, off);
  if (lane == 0) out[r] = mode ? 1.0f / fmaxf(sqrtf(ss), 1e-12f) : ss;
}

// ---------------- kernel 2: distance GEMM + argmax + gather/transpose ----------------
__global__ __launch_bounds__(256) void vq_main(const float* __restrict__ x,
                                               const float* __restrict__ embed,
                                               const float* __restrict__ esq,
                                               const float* __restrict__ invn,
                                               float* __restrict__ out_ind,
                                               float* __restrict__ out_q) {
  __shared__ float As[BM * LSTR];
  __shared__ float Bs[BN * LSTR];
  __shared__ int lds_idx[BM];

  const int tid = threadIdx.x;
  const int tx = tid & 15;        // code group
  const int ty = tid >> 4;        // row group
  const int n0 = blockIdx.x * BM; // 64 consecutive rows (stay within one b: T%64==0)

  float inv[4];
  #pragma unroll
  for (int i = 0; i < 4; ++i) inv[i] = invn[n0 + ty + 16*i];

  float best_s[4];
  int   best_i[4];
  #pragma unroll
  for (int i = 0; i < 4; ++i) { best_s[i] = -1e30f; best_i[i] = 0; }

  const int srow = tid >> 4;        // staging: row 0..15 (+p*16)
  const int sc4  = (tid & 15) * 4;  // staging: d offset 0..60

  for (int k0 = 0; k0 < KK; k0 += BN) {
    float acc[4][4];
    #pragma unroll
    for (int i = 0; i < 4; ++i)
      #pragma unroll
      for (int j = 0; j < 4; ++j) acc[i][j] = 0.f;

    for (int d0 = 0; d0 < DDIM; d0 += BD) {
      // ---- stage A (64 rows x 64 d) and B (64 codes x 64 d), coalesced float4 ----
      #pragma unroll
      for (int p = 0; p < 4; ++p) {
        int rr = srow + p*16;
        float4 a = *(const float4*)(x     + (size_t)(n0 + rr)*DDIM + d0 + sc4);
        *(float4*)(As + rr*LSTR + sc4) = a;
        float4 bv = *(const float4*)(embed + (size_t)(k0 + rr)*DDIM + d0 + sc4);
        *(float4*)(Bs + rr*LSTR + sc4) = bv;
      }
      __syncthreads();
      // ---- 4x4 register-blocked dot-product accumulation ----
      #pragma unroll
      for (int dd = 0; dd < BD; dd += 4) {
        float4 a4[4], b4[4];
        #pragma unroll
        for (int i = 0; i < 4; ++i) a4[i] = *(const float4*)(As + (ty + 16*i)*LSTR + dd);
        #pragma unroll
        for (int j = 0; j < 4; ++j) b4[j] = *(const float4*)(Bs + (tx + 16*j)*LSTR + dd);
        #pragma unroll
        for (int i = 0; i < 4; ++i)
          #pragma unroll
          for (int j = 0; j < 4; ++j)
            acc[i][j] += a4[i].x*b4[j].x + a4[i].y*b4[j].y
                       + a4[i].z*b4[j].z + a4[i].w*b4[j].w;
      }
      __syncthreads();
    }
    // ---- running argmax of score = 2*dot*inv_norm - ||e||^2 (k ascending => first-max kept) ----
    #pragma unroll
    for (int j = 0; j < 4; ++j) {
      int c = k0 + tx + 16*j;
      float es = esq[c];
      #pragma unroll
      for (int i = 0; i < 4; ++i) {
        float s = 2.0f * acc[i][j] * inv[i] - es;
        if (s > best_s[i]) { best_s[i] = s; best_i[i] = c; }
      }
    }
  }

  // ---- reduce (score, idx) across the 16 tx lanes sharing each row ----
  #pragma unroll
  for (int i = 0; i < 4; ++i) {
    float s = best_s[i]; int bi = best_i[i];
    #pragma unroll
    for (int off = 8; off; off >>= 1) {
      float s2 = __shfl_xor(s, off);
      int   i2 = __shfl_xor(bi, off);
      if (s2 > s || (s2 == s && i2 < bi)) { s = s2; bi = i2; }
    }
    if (tx == 0) {
      lds_idx[ty + 16*i] = bi;
      out_ind[n0 + ty + 16*i] = (float)bi;   // int output stored as float values
    }
  }

  // ---- fused gather + transpose: out_q[b][d][t] = embed[idx[t]][d] ----
  const int bb = n0 / TT;
  const int t0 = n0 % TT;
  const int w = tid >> 6;      // wave 0..3
  const int lane = tid & 63;   // d lane within 64-chunk
  float* trans = As;           // 64*65 floats fits in As (64*68)

  for (int d0 = 0; d0 < DDIM; d0 += 64) {
    __syncthreads();           // also orders lds_idx writes before first reads
    #pragma unroll
    for (int q = 0; q < 16; ++q) {
      int tt2 = w*16 + q;
      int e = lds_idx[tt2];
      trans[lane*65 + tt2] = embed[(size_t)e*DDIM + d0 + lane];  // coalesced read
    }
    __syncthreads();
    #pragma unroll
    for (int q = 0; q < 4; ++q) {
      int dl = (tid >> 4)*4 + q;
      int t4 = (tid & 15)*4;
      float4 o;
      o.x = trans[dl*65 + t4 + 0];
      o.y = trans[dl*65 + t4 + 1];
      o.z = trans[dl*65 + t4 + 2];
      o.w = trans[dl*65 + t4 + 3];
      *(float4*)(out_q + ((size_t)bb*DDIM + d0 + dl)*TT + t0 + t4) = o;  // coalesced write
    }
  }
}

extern "C" void kernel_launch(void* const* d_in, const int* in_sizes, int n_in,
                              void* d_out, int out_size, void* d_ws, size_t ws_size,
                              hipStream_t stream) {
  const float* x     = (const float*)d_in[0];
  const float* embed = (const float*)d_in[1];
  float* esq  = (float*)d_ws;          // 4096 floats
  float* invn = esq + KK;              // 32768 floats
  float* out_ind = (float*)d_out;      // 32768 indices as floats
  float* out_q   = out_ind + NN;       // 8*512*4096 quantize values

  rowss_kernel<<<KK/4, 256, 0, stream>>>(embed, esq, 0);
  rowss_kernel<<<NN/4, 256, 0, stream>>>(x, invn, 1);
  vq_main<<<NN/BM, 256, 0, stream>>>(x, embed, esq, invn, out_ind, out_q);
}

// Round 2
// 326.907 us; speedup vs baseline: 11.4786x; 11.4786x over previous
//
#include <hip/hip_runtime.h>
#include <math.h>

#define BB 8
#define TT 4096
#define DDIM 512
#define KK 4096
#define NN (BB*TT)
#define EPS 0.05f

typedef __attribute__((ext_vector_type(8))) short bf16x8;
typedef __attribute__((ext_vector_type(4))) float f32x4;

__device__ __forceinline__ void async16(void* lds, const void* g) {
  __builtin_amdgcn_global_load_lds((const __attribute__((address_space(1))) void*)g,
                                   (__attribute__((address_space(3))) void*)lds, 16, 0, 0);
}

__device__ __forceinline__ unsigned pk_bf16(float a, float b) {
  unsigned ua = __float_as_uint(a); ua += 0x7FFFu + ((ua >> 16) & 1u);
  unsigned ub = __float_as_uint(b); ub += 0x7FFFu + ((ub >> 16) & 1u);
  return (ua >> 16) | (ub & 0xFFFF0000u);
}

// ---------- prep: row sum-sq (esq or inv2=2/norm) + bf16 (RTNE) conversion ----------
__global__ __launch_bounds__(256) void prep_kernel(const float* __restrict__ src,
                                                   short* __restrict__ dst16,
                                                   float* __restrict__ outv, int mode) {
  int r = blockIdx.x * 4 + (threadIdx.x >> 6);
  int lane = threadIdx.x & 63;
  const float4* row4 = (const float4*)(src + (size_t)r * DDIM);
  float4 v0 = row4[lane];
  float4 v1 = row4[lane + 64];
  uint2 p0, p1;
  p0.x = pk_bf16(v0.x, v0.y); p0.y = pk_bf16(v0.z, v0.w);
  p1.x = pk_bf16(v1.x, v1.y); p1.y = pk_bf16(v1.z, v1.w);
  *(uint2*)(dst16 + (size_t)r * DDIM + lane * 4) = p0;
  *(uint2*)(dst16 + (size_t)r * DDIM + 256 + lane * 4) = p1;
  float ss = v0.x*v0.x + v0.y*v0.y + v0.z*v0.z + v0.w*v0.w
           + v1.x*v1.x + v1.y*v1.y + v1.z*v1.z + v1.w*v1.w;
  #pragma unroll
  for (int off = 32; off; off >>= 1) ss += __shfl_down(ss, off);
  if (lane == 0) outv[r] = mode ? 2.0f / fmaxf(sqrtf(ss), 1e-12f) : ss;
}

// ---------- main MFMA pass: approx scores + per-row top-2 ----------
// grid 1024: bid&255 = m-block (128 rows), bid>>8 = k-quarter (1024 codes)
__global__ __launch_bounds__(256, 2) void vq_mfma(const short* __restrict__ xb,
                                                  const short* __restrict__ eb,
                                                  const float* __restrict__ esq,
                                                  const float* __restrict__ inv2,
                                                  float4* __restrict__ top2) {
  __shared__ short As[128 * 64];
  __shared__ short Bs[128 * 64];
  __shared__ float rS1[2][128];
  __shared__ float rS2[2][128];
  __shared__ int   rI1[2][128];

  const int tid = threadIdx.x;
  const int lane = tid & 63;
  const int w = tid >> 6;
  const int wr = w >> 1, wc = w & 1;
  const int q = lane >> 4, c16 = lane & 15;

  const int mb = blockIdx.x & 255;
  const int kq = blockIdx.x >> 8;
  const int n0 = mb * 128;
  const int kbase = kq * 1024;

  // staging constants: lane fills LDS row (w*32+i*8+(lane>>3)), chunk (lane&7);
  // source column chunk XOR-swizzled by row&7 (== lane>>3) to kill bank conflicts
  const int srow = w * 32 + (lane >> 3);
  const int scol = ((lane & 7) ^ (lane >> 3)) * 8;
  const short* gA = xb + (size_t)(n0 + srow) * DDIM + scol;

  float s1[16], s2v[16];
  int   i1[16];
  #pragma unroll
  for (int s = 0; s < 16; ++s) { s1[s] = -3e38f; s2v[s] = -3e38f; i1[s] = 0; }

  float4 inv4[4];
  #pragma unroll
  for (int ti = 0; ti < 4; ++ti)
    inv4[ti] = *(const float4*)&inv2[n0 + wr * 64 + ti * 16 + q * 4];

  for (int c = 0; c < 8; ++c) {
    const int k0c = kbase + c * 128;
    const short* gB = eb + (size_t)(k0c + srow) * DDIM + scol;
    f32x4 acc[4][4];
    #pragma unroll
    for (int ti = 0; ti < 4; ++ti)
      #pragma unroll
      for (int tj = 0; tj < 4; ++tj) acc[ti][tj] = (f32x4){0.f, 0.f, 0.f, 0.f};

    for (int d0 = 0; d0 < DDIM; d0 += 64) {
      #pragma unroll
      for (int i = 0; i < 4; ++i) {
        async16(As + (w * 32 + i * 8) * 64, gA + (size_t)i * 8 * DDIM + d0);
        async16(Bs + (w * 32 + i * 8) * 64, gB + (size_t)i * 8 * DDIM + d0);
      }
      __syncthreads();
      #pragma unroll
      for (int ks = 0; ks < 2; ++ks) {
        const int ko = (((ks << 2) | q) ^ (lane & 7)) << 3;  // swizzled k-chunk
        bf16x8 af[4], bf[4];
        #pragma unroll
        for (int ti = 0; ti < 4; ++ti)
          af[ti] = *(const bf16x8*)&As[(wr * 64 + ti * 16 + c16) * 64 + ko];
        #pragma unroll
        for (int tj = 0; tj < 4; ++tj)
          bf[tj] = *(const bf16x8*)&Bs[(wc * 64 + tj * 16 + c16) * 64 + ko];
        #pragma unroll
        for (int ti = 0; ti < 4; ++ti)
          #pragma unroll
          for (int tj = 0; tj < 4; ++tj)
            acc[ti][tj] = __builtin_amdgcn_mfma_f32_16x16x32_bf16(af[ti], bf[tj], acc[ti][tj], 0, 0, 0);
      }
      __syncthreads();
    }
    // epilogue: score = acc*inv2 - esq, update per-row top-2
    #pragma unroll
    for (int tj = 0; tj < 4; ++tj) {
      const int col = k0c + wc * 64 + tj * 16 + c16;
      const float nes = -esq[col];
      #pragma unroll
      for (int ti = 0; ti < 4; ++ti)
        #pragma unroll
        for (int r = 0; r < 4; ++r) {
          int slot = ti * 4 + r;
          float sc = fmaf(acc[ti][tj][r], inv4[ti][r], nes);
          float mn = fminf(sc, s1[slot]);
          s2v[slot] = fmaxf(s2v[slot], mn);
          if (sc > s1[slot]) { s1[slot] = sc; i1[slot] = col; }
        }
    }
  }

  // reduce across the 16 lanes sharing each row (same q, varying lane&15)
  #pragma unroll
  for (int slot = 0; slot < 16; ++slot) {
    float a1 = s1[slot], a2 = s2v[slot]; int ai = i1[slot];
    #pragma unroll
    for (int off = 1; off < 16; off <<= 1) {
      float b1 = __shfl_xor(a1, off);
      float b2 = __shfl_xor(a2, off);
      int   bi = __shfl_xor(ai, off);
      float mn = fminf(a1, b1);
      a2 = fmaxf(fmaxf(a2, b2), mn);
      if (b1 > a1 || (b1 == a1 && bi < ai)) { a1 = b1; ai = bi; }
    }
    if (c16 == 0) {
      int row = wr * 64 + (slot >> 2) * 16 + q * 4 + (slot & 3);
      rS1[wc][row] = a1; rS2[wc][row] = a2; rI1[wc][row] = ai;
    }
  }
  __syncthreads();
  if (tid < 128) {
    float a1 = rS1[0][tid], a2 = rS2[0][tid]; int ai = rI1[0][tid];
    float b1 = rS1[1][tid], b2 = rS2[1][tid]; int bi = rI1[1][tid];
    float mn = fminf(a1, b1);
    a2 = fmaxf(fmaxf(a2, b2), mn);
    if (b1 > a1 || (b1 == a1 && bi < ai)) { a1 = b1; ai = bi; }
    top2[(size_t)kq * NN + n0 + tid] = make_float4(a1, __int_as_float(ai), a2, 0.f);
  }
}

// ---------- finalize: merge 4 k-quarters, write idx, flag small-margin rows ----------
__global__ __launch_bounds__(256) void finalize_kernel(const float4* __restrict__ top2,
                                                       float* __restrict__ out_ind,
                                                       int* __restrict__ flags,
                                                       int* __restrict__ list,
                                                       int* __restrict__ cnt) {
  int row = blockIdx.x * 256 + threadIdx.x;
  float a1 = -3e38f, a2 = -3e38f; int ai = 0;
  #pragma unroll
  for (int kq = 0; kq < 4; ++kq) {
    float4 t = top2[(size_t)kq * NN + row];
    float b1 = t.x, b2 = t.z; int bi = __float_as_int(t.y);
    float mn = fminf(a1, b1);
    a2 = fmaxf(fmaxf(a2, b2), mn);
    if (b1 > a1 || (b1 == a1 && bi < ai)) { a1 = b1; ai = bi; }
  }
  out_ind[row] = (float)ai;
  if (a1 - a2 < EPS) {
    int p = atomicAdd(cnt, 1);
    list[p] = row;
    flags[row] = p + 1;
  } else {
    flags[row] = 0;
  }
}

// ---------- cleanup: exact fp32 rescore of flagged rows (split 8 k-chunks) ----------
__global__ __launch_bounds__(256) void cleanup_kernel(const float* __restrict__ x,
                                                      const float* __restrict__ embed,
                                                      const float* __restrict__ esq,
                                                      const float* __restrict__ inv2,
                                                      const int* __restrict__ list,
                                                      const int* __restrict__ cnt,
                                                      float2* __restrict__ exact) {
  __shared__ float xr[DDIM];
  __shared__ float red_s[4];
  __shared__ int   red_i[4];
  const int rs = blockIdx.x & 31, kc = blockIdx.x >> 5;
  const int tid = threadIdx.x;
  const int lane = tid & 63, wid = tid >> 6;
  const int n = *cnt;
  for (int ii = rs; ii < n; ii += 32) {
    const int row = list[ii];
    __syncthreads();
    if (tid < 128) *(float4*)&xr[tid * 4] = *(const float4*)&x[(size_t)row * DDIM + tid * 4];
    __syncthreads();
    const float iv = inv2[row];
    float bs = -3e38f; int bi = 0;
    for (int cc = 0; cc < 2; ++cc) {
      const int code = kc * 512 + cc * 256 + tid;
      const float4* er = (const float4*)&embed[(size_t)code * DDIM];
      float acc = 0.f;
      for (int d = 0; d < DDIM / 4; ++d) {
        float4 e4 = er[d];
        float4 x4 = *(const float4*)&xr[d * 4];
        acc += x4.x * e4.x + x4.y * e4.y + x4.z * e4.z + x4.w * e4.w;
      }
      float sc = fmaf(acc, iv, -esq[code]);
      if (sc > bs || (sc == bs && code < bi)) { bs = sc; bi = code; }
    }
    #pragma unroll
    for (int off = 1; off < 64; off <<= 1) {
      float b1 = __shfl_xor(bs, off);
      int   b2 = __shfl_xor(bi, off);
      if (b1 > bs || (b1 == bs && b2 < bi)) { bs = b1; bi = b2; }
    }
    if (lane == 0) { red_s[wid] = bs; red_i[wid] = bi; }
    __syncthreads();
    if (tid == 0) {
      for (int ww = 1; ww < 4; ++ww)
        if (red_s[ww] > red_s[0] || (red_s[ww] == red_s[0] && red_i[ww] < red_i[0])) {
          red_s[0] = red_s[ww]; red_i[0] = red_i[ww];
        }
      exact[(size_t)ii * 8 + kc] = make_float2(red_s[0], (float)red_i[0]);
    }
  }
}

// ---------- gather + transpose (merges exact results for flagged rows) ----------
__global__ __launch_bounds__(256) void gather_kernel(const float* __restrict__ embed,
                                                     const int* __restrict__ flags,
                                                     const float2* __restrict__ exact,
                                                     float* __restrict__ out_ind,
                                                     float* __restrict__ out_q) {
  __shared__ int lidx[64];
  __shared__ float trans[64 * 65];
  const int n0 = blockIdx.x * 64;
  const int tid = threadIdx.x;
  if (tid < 64) {
    const int row = n0 + tid;
    const int f = flags[row];
    int idx;
    if (f) {
      float bsv = -3e38f; int bi = 0;
      const float2* e8 = &exact[(size_t)(f - 1) * 8];
      #pragma unroll
      for (int k = 0; k < 8; ++k) {
        float2 t = e8[k];
        int ci = (int)t.y;
        if (t.x > bsv || (t.x == bsv && ci < bi)) { bsv = t.x; bi = ci; }
      }
      idx = bi;
      out_ind[row] = (float)idx;
    } else {
      idx = (int)out_ind[row];
    }
    lidx[tid] = idx;
  }
  __syncthreads();
  const int bb = n0 >> 12;
  const int t0 = n0 & (TT - 1);
  const int w = tid >> 6, lane = tid & 63;
  for (int d0 = 0; d0 < DDIM; d0 += 64) {
    if (d0) __syncthreads();
    #pragma unroll
    for (int qq = 0; qq < 16; ++qq) {
      int tt2 = w * 16 + qq;
      int e = lidx[tt2];
      trans[lane * 65 + tt2] = embed[(size_t)e * DDIM + d0 + lane];
    }
    __syncthreads();
    #pragma unroll
    for (int qq = 0; qq < 4; ++qq) {
      int dl = (tid >> 4) * 4 + qq;
      int t4 = (tid & 15) * 4;
      float4 o;
      o.x = trans[dl * 65 + t4 + 0];
      o.y = trans[dl * 65 + t4 + 1];
      o.z = trans[dl * 65 + t4 + 2];
      o.w = trans[dl * 65 + t4 + 3];
      *(float4*)&out_q[((size_t)bb * DDIM + d0 + dl) * TT + t0 + t4] = o;
    }
  }
}

extern "C" void kernel_launch(void* const* d_in, const int* in_sizes, int n_in,
                              void* d_out, int out_size, void* d_ws, size_t ws_size,
                              hipStream_t stream) {
  const float* x     = (const float*)d_in[0];
  const float* embed = (const float*)d_in[1];
  char* ws = (char*)d_ws;
  short* xb      = (short*)(ws);                         // 33,554,432 B
  short* eb      = (short*)(ws + 33554432);              //  4,194,304 B
  float* esq     = (float*)(ws + 37748736);              //     16,384 B
  float* inv2    = (float*)(ws + 37765120);              //    131,072 B
  float4* top2   = (float4*)(ws + 37896192);             //  2,097,152 B
  int* list      = (int*)(ws + 39993344);                //    131,072 B
  int* flags     = (int*)(ws + 40124416);                //    131,072 B
  float2* exact  = (float2*)(ws + 40255488);             //  2,097,152 B
  int* cnt       = (int*)(ws + 42352640);                //          4 B

  float* out_ind = (float*)d_out;
  float* out_q   = out_ind + NN;

  prep_kernel<<<KK / 4, 256, 0, stream>>>(embed, eb, esq, 0);
  prep_kernel<<<NN / 4, 256, 0, stream>>>(x, xb, inv2, 1);
  hipMemsetAsync(cnt, 0, 4, stream);
  vq_mfma<<<1024, 256, 0, stream>>>(xb, eb, esq, inv2, top2);
  finalize_kernel<<<NN / 256, 256, 0, stream>>>(top2, out_ind, flags, list, cnt);
  cleanup_kernel<<<256, 256, 0, stream>>>(x, embed, esq, inv2, list, cnt, exact);
  gather_kernel<<<NN / 64, 256, 0, stream>>>(embed, flags, exact, out_ind, out_q);
}